// Round 1
// baseline (34349.341 us; speedup 1.0000x reference)
//
#include <hip/hip_runtime.h>
#include <hip/hip_cooperative_groups.h>

namespace cg = cooperative_groups;

// Problem dims (fixed by the reference)
constexpr int Bdim = 128;   // batch
constexpr int Tdim = 512;   // time steps
constexpr int Fdim = 256;   // input features
constexpr int Hdim = 512;   // hidden
// Grid decomposition
constexpr int JBn = 16;     // j-slice blocks (columns of H)
constexpr int BBn = 16;     // b-slice blocks
constexpr int BSn = 8;      // batch rows per block
constexpr int JSn = 32;     // H-columns per gate per block
constexpr float EPSc = 1e-8f;
constexpr float CLAMPc = 10.0f;

__global__ __launch_bounds__(256, 1) void slstm_coop(
    const float* __restrict__ x,
    const float* __restrict__ Wf, const float* __restrict__ bfv,
    const float* __restrict__ Wi, const float* __restrict__ biv,
    const float* __restrict__ Wo, const float* __restrict__ bov,
    const float* __restrict__ Wz, const float* __restrict__ bzv,
    const float* __restrict__ Rf, const float* __restrict__ Ri,
    const float* __restrict__ Ro, const float* __restrict__ Rz,
    const float* __restrict__ fcw, const float* __restrict__ fcb,
    float* __restrict__ hb0, float* __restrict__ hb1,
    float* __restrict__ out)
{
    cg::grid_group grid = cg::this_grid();

    const int tid = threadIdx.x;
    const int jb  = blockIdx.x % JBn;   // same-jb blocks land on one XCD (blockIdx % 8 const)
    const int bb  = blockIdx.x / JBn;

    // --- dot-product phase identity: wave = gate, lane -> (bh, tj) ---
    const int g    = tid >> 6;          // 0..3 : f,i,o,z (one gate per wave)
    const int lane = tid & 63;
    const int tj   = lane & 31;         // column within slice
    const int bh   = lane >> 5;         // batch half: handles b = bh*4 .. bh*4+3
    const int col  = jb * JSn + tj;     // global H column

    const float* Wg = (g == 0) ? Wf : (g == 1) ? Wi : (g == 2) ? Wo : Wz;
    const float* Rg = (g == 0) ? Rf : (g == 1) ? Ri : (g == 2) ? Ro : Rz;
    const float* bg = (g == 0) ? bfv : (g == 1) ? biv : (g == 2) ? bov : bzv;
    const float bias = bg[col];

    // --- elementwise phase identity: thread -> (tb2, tj2) ---
    const int tb2 = tid >> 5;           // 0..7 local batch row
    const int tj2 = tid & 31;
    const int bglob2 = bb * BSn + tb2;

    float c_st = 0.0f;                  // per-(b,j) cell state, lives in regs all 512 steps
    float n_st = 0.0f;

    __shared__ float in_s[BSn][Fdim + Hdim];   // [8][768] = 24 KB
    __shared__ float dots_s[4][BSn][JSn];      // 4 KB gate-exchange buffer

    for (int t = 0; t < Tdim; ++t) {
        // ---- stage x_t and h_prev into LDS (coalesced float4) ----
        {
            #pragma unroll
            for (int i = 0; i < 2; ++i) {
                int f4 = tid + i * 256;            // 0..511 float4s of x slice
                int b  = f4 >> 6;                  // 64 float4 per row
                int fi = f4 & 63;
                float4 v = *reinterpret_cast<const float4*>(
                    x + ((size_t)(bb * BSn + b) * Tdim + t) * Fdim + fi * 4);
                *reinterpret_cast<float4*>(&in_s[b][fi * 4]) = v;
            }
            if (t == 0) {
                #pragma unroll
                for (int i = 0; i < 4; ++i) {
                    int f4 = tid + i * 256;        // 0..1023 float4s of h slice
                    int b  = f4 >> 7;              // 128 float4 per row
                    int hi = f4 & 127;
                    *reinterpret_cast<float4*>(&in_s[b][Fdim + hi * 4]) =
                        make_float4(0.f, 0.f, 0.f, 0.f);
                }
            } else {
                const float* hprev = (t & 1) ? hb1 : hb0;
                #pragma unroll
                for (int i = 0; i < 4; ++i) {
                    int f4 = tid + i * 256;
                    int b  = f4 >> 7;
                    int hi = f4 & 127;
                    float4 v = *reinterpret_cast<const float4*>(
                        hprev + (size_t)(bb * BSn + b) * Hdim + hi * 4);
                    *reinterpret_cast<float4*>(&in_s[b][Fdim + hi * 4]) = v;
                }
            }
        }
        __syncthreads();

        // ---- 4 batch-row dot products for (gate g, column col) ----
        float acc0 = 0.f, acc1 = 0.f, acc2 = 0.f, acc3 = 0.f;
        const int b0 = bh * 4;

        // x-projection part: K = 0..255
        for (int k = 0; k < Fdim; k += 4) {
            float w0 = Wg[(size_t)(k + 0) * Hdim + col];
            float w1 = Wg[(size_t)(k + 1) * Hdim + col];
            float w2 = Wg[(size_t)(k + 2) * Hdim + col];
            float w3 = Wg[(size_t)(k + 3) * Hdim + col];
            float4 a0 = *reinterpret_cast<const float4*>(&in_s[b0 + 0][k]);
            float4 a1 = *reinterpret_cast<const float4*>(&in_s[b0 + 1][k]);
            float4 a2 = *reinterpret_cast<const float4*>(&in_s[b0 + 2][k]);
            float4 a3 = *reinterpret_cast<const float4*>(&in_s[b0 + 3][k]);
            acc0 += a0.x * w0 + a0.y * w1 + a0.z * w2 + a0.w * w3;
            acc1 += a1.x * w0 + a1.y * w1 + a1.z * w2 + a1.w * w3;
            acc2 += a2.x * w0 + a2.y * w1 + a2.z * w2 + a2.w * w3;
            acc3 += a3.x * w0 + a3.y * w1 + a3.z * w2 + a3.w * w3;
        }
        // recurrent part: K = 0..511 over h
        for (int k = 0; k < Hdim; k += 4) {
            float w0 = Rg[(size_t)(k + 0) * Hdim + col];
            float w1 = Rg[(size_t)(k + 1) * Hdim + col];
            float w2 = Rg[(size_t)(k + 2) * Hdim + col];
            float w3 = Rg[(size_t)(k + 3) * Hdim + col];
            float4 a0 = *reinterpret_cast<const float4*>(&in_s[b0 + 0][Fdim + k]);
            float4 a1 = *reinterpret_cast<const float4*>(&in_s[b0 + 1][Fdim + k]);
            float4 a2 = *reinterpret_cast<const float4*>(&in_s[b0 + 2][Fdim + k]);
            float4 a3 = *reinterpret_cast<const float4*>(&in_s[b0 + 3][Fdim + k]);
            acc0 += a0.x * w0 + a0.y * w1 + a0.z * w2 + a0.w * w3;
            acc1 += a1.x * w0 + a1.y * w1 + a1.z * w2 + a1.w * w3;
            acc2 += a2.x * w0 + a2.y * w1 + a2.z * w2 + a2.w * w3;
            acc3 += a3.x * w0 + a3.y * w1 + a3.z * w2 + a3.w * w3;
        }

        dots_s[g][b0 + 0][tj] = acc0 + bias;
        dots_s[g][b0 + 1][tj] = acc1 + bias;
        dots_s[g][b0 + 2][tj] = acc2 + bias;
        dots_s[g][b0 + 3][tj] = acc3 + bias;
        __syncthreads();

        // ---- elementwise sLSTM cell update (thread owns (tb2, tj2)) ----
        {
            float ft = dots_s[0][tb2][tj2];
            float it = dots_s[1][tb2][tj2];
            float ot = dots_s[2][tb2][tj2];
            float zt = dots_s[3][tb2][tj2];

            float o  = 1.0f / (1.0f + __expf(-ot));
            float z  = tanhf(zt);
            float fh = __expf(fminf(ft, CLAMPc));
            float ih = __expf(fminf(it, CLAMPc));
            float denom = fh + ih + EPSc;
            float f  = fh / denom;
            float ii = ih / denom;
            c_st = f * c_st + ii * z;
            n_st = f * n_st + ii;
            float hval = o * (c_st / (n_st + EPSc));

            float* hnext = (t & 1) ? hb0 : hb1;
            hnext[(size_t)bglob2 * Hdim + jb * JSn + tj2] = hval;
        }

        grid.sync();   // also orders the h writes for next step's reads
    }

    // ---- final fc: pos[b] = tanh(h . fc_w + fc_b), done by jb==0 blocks ----
    if (jb == 0) {
        const float* hfin = hb0;        // t=511 (odd) wrote hb0
        int bl = tid >> 5;              // 0..7
        int l  = tid & 31;
        float p = 0.f;
        for (int j = l; j < Hdim; j += 32)
            p += hfin[(size_t)(bb * BSn + bl) * Hdim + j] * fcw[j];
        p += __shfl_xor(p, 16);
        p += __shfl_xor(p, 8);
        p += __shfl_xor(p, 4);
        p += __shfl_xor(p, 2);
        p += __shfl_xor(p, 1);
        if (l == 0) out[bb * BSn + bl] = tanhf(p + fcb[0]);
    }
}

extern "C" void kernel_launch(void* const* d_in, const int* in_sizes, int n_in,
                              void* d_out, int out_size, void* d_ws, size_t ws_size,
                              hipStream_t stream) {
    const float* x   = (const float*)d_in[0];
    const float* Wf  = (const float*)d_in[1];
    const float* bf_ = (const float*)d_in[2];
    const float* Wi  = (const float*)d_in[3];
    const float* bi_ = (const float*)d_in[4];
    const float* Wo  = (const float*)d_in[5];
    const float* bo_ = (const float*)d_in[6];
    const float* Wz  = (const float*)d_in[7];
    const float* bz_ = (const float*)d_in[8];
    const float* Rf  = (const float*)d_in[9];
    const float* Ri  = (const float*)d_in[10];
    const float* Ro  = (const float*)d_in[11];
    const float* Rz  = (const float*)d_in[12];
    const float* fcw = (const float*)d_in[13];
    const float* fcb = (const float*)d_in[14];

    float* hb0 = (float*)d_ws;                 // [128][512]
    float* hb1 = hb0 + Bdim * Hdim;            // [128][512]  (1 MB total, well under ws)
    float* o   = (float*)d_out;

    void* args[] = { &x, &Wf, &bf_, &Wi, &bi_, &Wo, &bo_, &Wz, &bz_,
                     &Rf, &Ri, &Ro, &Rz, &fcw, &fcb, &hb0, &hb1, &o };

    hipLaunchCooperativeKernel(reinterpret_cast<void*>(slstm_coop),
                               dim3(JBn * BBn), dim3(256), args, 0, stream);
}

// Round 3
// 20123.267 us; speedup vs baseline: 1.7069x; 1.7069x over previous
//
#include <hip/hip_runtime.h>
#include <hip/hip_cooperative_groups.h>

namespace cg = cooperative_groups;

// Problem dims (fixed by the reference)
constexpr int Bdim = 128;
constexpr int Tdim = 512;
constexpr int Fdim = 256;
constexpr int Hdim = 512;
constexpr int Kdim = Fdim + Hdim;       // 768 concat [x | h]
// Decomposition: 256 blocks = 16 bb (8 batch rows) x 16 jb (32 H-cols, all 4 gates)
constexpr int NB   = 8;                 // batch rows per block
constexpr int CC   = 128;               // concat-cols per block = 4 gates * 32 H-cols
constexpr int NC   = 8;                 // cols per thread
constexpr int NK   = 24;                // k per thread  (768 / 32 k-groups)
constexpr float EPSc = 1e-8f;
constexpr float CLAMPc = 10.0f;

typedef _Float16 half2v __attribute__((ext_vector_type(2)));
typedef _Float16 half4v __attribute__((ext_vector_type(4)));

__device__ __forceinline__ float wave_sum4(float v) {
    // Sum across lanes {l, l^16, l^32, l^48} — the 4 k-subgroups in a wave.
    // Known-good __shfl_xor (proven in round 1); permlane variant retired
    // pending correctness root-cause.
    v += __shfl_xor(v, 16);
    v += __shfl_xor(v, 32);
    return v;
}

__global__ __launch_bounds__(512, 2) void slstm_persist(
    const float* __restrict__ x,
    const float* __restrict__ Wf, const float* __restrict__ bfv,
    const float* __restrict__ Wi, const float* __restrict__ biv,
    const float* __restrict__ Wo, const float* __restrict__ bov,
    const float* __restrict__ Wz, const float* __restrict__ bzv,
    const float* __restrict__ Rf, const float* __restrict__ Ri,
    const float* __restrict__ Ro, const float* __restrict__ Rz,
    const float* __restrict__ fcw, const float* __restrict__ fcb,
    float* __restrict__ hb0, float* __restrict__ hb1,
    float* __restrict__ out)
{
    cg::grid_group grid = cg::this_grid();

    const int tid = threadIdx.x;
    // XCD-aware swizzle: all 16 jb-blocks of one bb land on one XCD (perf only)
    const int xcd  = blockIdx.x & 7;
    const int slot = blockIdx.x >> 3;        // 0..31
    const int bb   = xcd * 2 + (slot & 1);   // 0..15
    const int jb   = slot >> 1;              // 0..15

    const int kg   = tid >> 4;               // 0..31 k-group
    const int colg = tid & 15;               // 0..15 col-group
    const int wv   = tid >> 6;               // wave 0..7
    const int k0   = kg * NK;

    // ---------------- prologue: stationary weights -> f16 pair registers ----
    half2v wpk[NC][NK / 2];
    #pragma unroll
    for (int ci = 0; ci < NC; ++ci) {
        const int cc   = colg * NC + ci;         // 0..127
        const int g    = cc >> 5;                // gate
        const int hcol = jb * 32 + (cc & 31);    // global H column
        const float* Wg = (g == 0) ? Wf : (g == 1) ? Wi : (g == 2) ? Wo : Wz;
        const float* Rg = (g == 0) ? Rf : (g == 1) ? Ri : (g == 2) ? Ro : Rz;
        #pragma unroll
        for (int j = 0; j < NK / 2; ++j) {
            const int k = k0 + 2 * j;            // even; pair never spans 256
            float w0, w1;
            if (k < Fdim) {
                w0 = Wg[(size_t)k * Hdim + hcol];
                w1 = Wg[(size_t)(k + 1) * Hdim + hcol];
            } else {
                w0 = Rg[(size_t)(k - Fdim) * Hdim + hcol];
                w1 = Rg[(size_t)(k + 1 - Fdim) * Hdim + hcol];
            }
            wpk[ci][j] = half2v{(_Float16)w0, (_Float16)w1};   // RTN
        }
    }

    // cell-update thread identity (tid < 256): (b, hc)
    const int ub  = tid >> 5;                // 0..7
    const int uhc = tid & 31;                // 0..31
    float bias_f = 0.f, bias_i = 0.f, bias_o = 0.f, bias_z = 0.f;
    if (tid < 256) {
        bias_f = bfv[jb * 32 + uhc];
        bias_i = biv[jb * 32 + uhc];
        bias_o = bov[jb * 32 + uhc];
        bias_z = bzv[jb * 32 + uhc];
    }
    float c_st = 0.f, n_st = 0.f;

    __shared__ _Float16 in_s[NB][Kdim];          // 12 KB  f16 [x | h]
    __shared__ float    part_s[8][NB][CC];       // 32 KB  per-wave partials

    for (int t = 0; t < Tdim; ++t) {
        // ---- stage x_t (f32 -> f16 RTN) ----
        {
            const int b  = tid >> 6;
            const int f4 = tid & 63;
            float4 v = *reinterpret_cast<const float4*>(
                x + ((size_t)(bb * NB + b) * Tdim + t) * Fdim + f4 * 4);
            half4v pk = half4v{(_Float16)v.x, (_Float16)v.y,
                               (_Float16)v.z, (_Float16)v.w};
            *reinterpret_cast<half4v*>(&in_s[b][f4 * 4]) = pk;
        }
        // ---- stage h_prev (f32 -> f16 RTN) ----
        if (t == 0) {
            #pragma unroll
            for (int i = 0; i < 2; ++i) {
                int idx = tid + i * 512;
                int b = idx >> 7, h4 = idx & 127;
                *reinterpret_cast<half4v*>(&in_s[b][Fdim + h4 * 4]) =
                    half4v{(_Float16)0.f, (_Float16)0.f, (_Float16)0.f, (_Float16)0.f};
            }
        } else {
            const float* hprev = (t & 1) ? hb1 : hb0;
            #pragma unroll
            for (int i = 0; i < 2; ++i) {
                int idx = tid + i * 512;
                int b = idx >> 7, h4 = idx & 127;
                float4 v = *reinterpret_cast<const float4*>(
                    hprev + (size_t)(bb * NB + b) * Hdim + h4 * 4);
                half4v pk = half4v{(_Float16)v.x, (_Float16)v.y,
                                   (_Float16)v.z, (_Float16)v.w};
                *reinterpret_cast<half4v*>(&in_s[b][Fdim + h4 * 4]) = pk;
            }
        }
        __syncthreads();

        // ---- dot2 inner loop: 384 fdot2 (768 MACs) per thread ----
        float acc[NC][NB];
        #pragma unroll
        for (int ci = 0; ci < NC; ++ci)
            #pragma unroll
            for (int b = 0; b < NB; ++b) acc[ci][b] = 0.f;

        #pragma unroll
        for (int b = 0; b < NB; ++b) {
            const half2v* p = reinterpret_cast<const half2v*>(&in_s[b][k0]);
            half2v hp[12];
            #pragma unroll
            for (int j = 0; j < 12; ++j) hp[j] = p[j];
            #pragma unroll
            for (int ci = 0; ci < NC; ++ci) {
                #pragma unroll
                for (int j = 0; j < NK / 2; ++j) {
                    acc[ci][b] = __builtin_amdgcn_fdot2(
                        wpk[ci][j], hp[j], acc[ci][b], false);
                }
            }
        }

        // ---- reduce across the 4 k-subgroups within the wave ----
        #pragma unroll
        for (int ci = 0; ci < NC; ++ci)
            #pragma unroll
            for (int b = 0; b < NB; ++b)
                acc[ci][b] = wave_sum4(acc[ci][b]);

        // each of the 4 duplicate lane-groups writes 2 batch rows
        {
            const int kgl = (tid >> 4) & 3;
            #pragma unroll
            for (int bs = 0; bs < 2; ++bs) {
                const int b = kgl * 2 + bs;
                #pragma unroll
                for (int cp = 0; cp < NC / 2; ++cp) {
                    float2 w2 = make_float2(acc[2 * cp][b], acc[2 * cp + 1][b]);
                    *reinterpret_cast<float2*>(&part_s[wv][b][colg * NC + 2 * cp]) = w2;
                }
            }
        }
        __syncthreads();

        // ---- cross-wave reduce + bias + cell update (tid < 256) ----
        if (tid < 256) {
            float pre[4];
            #pragma unroll
            for (int g = 0; g < 4; ++g) {
                float s = 0.f;
                #pragma unroll
                for (int w = 0; w < 8; ++w) s += part_s[w][ub][g * 32 + uhc];
                pre[g] = s;
            }
            pre[0] += bias_f; pre[1] += bias_i; pre[2] += bias_o; pre[3] += bias_z;

            float o  = 1.0f / (1.0f + __expf(-pre[2]));
            float z  = tanhf(pre[3]);
            float fh = __expf(fminf(pre[0], CLAMPc));
            float ih = __expf(fminf(pre[1], CLAMPc));
            float denom = fh + ih + EPSc;
            float f  = fh / denom;
            float ii = ih / denom;
            c_st = f * c_st + ii * z;
            n_st = f * n_st + ii;
            float hval = o * (c_st / (n_st + EPSc));

            float* hnext = (t & 1) ? hb0 : hb1;
            hnext[(size_t)(bb * NB + ub) * Hdim + jb * 32 + uhc] = hval;
        }
        __syncthreads();    // part_s / in_s reuse next step
        grid.sync();        // h visible to all blocks
    }

    // ---- final fc: out[b] = tanh(h . fc_w + fc_b), jb==0 blocks only ----
    if (jb == 0) {
        const int row = bb * NB + wv;       // one wave per batch row
        const int l   = tid & 63;
        float p = 0.f;
        #pragma unroll
        for (int s = 0; s < 8; ++s)
            p += hb0[(size_t)row * Hdim + l + s * 64] * fcw[l + s * 64];
        p += __shfl_xor(p, 32);
        p += __shfl_xor(p, 16);
        p += __shfl_xor(p, 8);
        p += __shfl_xor(p, 4);
        p += __shfl_xor(p, 2);
        p += __shfl_xor(p, 1);
        if (l == 0) out[row] = tanhf(p + fcb[0]);
    }
}

extern "C" void kernel_launch(void* const* d_in, const int* in_sizes, int n_in,
                              void* d_out, int out_size, void* d_ws, size_t ws_size,
                              hipStream_t stream) {
    const float* x   = (const float*)d_in[0];
    const float* Wf  = (const float*)d_in[1];
    const float* bf_ = (const float*)d_in[2];
    const float* Wi  = (const float*)d_in[3];
    const float* bi_ = (const float*)d_in[4];
    const float* Wo  = (const float*)d_in[5];
    const float* bo_ = (const float*)d_in[6];
    const float* Wz  = (const float*)d_in[7];
    const float* bz_ = (const float*)d_in[8];
    const float* Rf  = (const float*)d_in[9];
    const float* Ri  = (const float*)d_in[10];
    const float* Ro  = (const float*)d_in[11];
    const float* Rz  = (const float*)d_in[12];
    const float* fcw = (const float*)d_in[13];
    const float* fcb = (const float*)d_in[14];

    float* hb0 = (float*)d_ws;                  // [128][512] f32
    float* hb1 = hb0 + Bdim * Hdim;
    float* o   = (float*)d_out;

    void* args[] = { &x, &Wf, &bf_, &Wi, &bi_, &Wo, &bo_, &Wz, &bz_,
                     &Rf, &Ri, &Ro, &Rz, &fcw, &fcb, &hb0, &hb1, &o };

    hipLaunchCooperativeKernel(reinterpret_cast<void*>(slstm_persist),
                               dim3(256), dim3(512), args, 0, stream);
}

// Round 4
// 4970.273 us; speedup vs baseline: 6.9110x; 4.0487x over previous
//
#include <hip/hip_runtime.h>

// Problem dims (fixed by the reference)
constexpr int Bdim = 128;
constexpr int Tdim = 512;
constexpr int Fdim = 256;
constexpr int Hdim = 512;
constexpr int Kdim = Fdim + Hdim;       // 768 concat [x | h]
// Decomposition: 256 blocks = 16 bb (8 batch rows) x 16 jb (32 H-cols, all 4 gates)
constexpr int NB   = 8;                 // batch rows per block
constexpr int CC   = 128;               // concat-cols per block = 4 gates * 32 H-cols
constexpr int NC   = 8;                 // cols per thread
constexpr int NK   = 24;                // k per thread  (768 / 32 k-groups)
constexpr float EPSc = 1e-8f;
constexpr float CLAMPc = 10.0f;

// ws layout: [0,32KB) flags (int @ 128B stride); [32KB, 32KB+128KB) hbuf u64[2][16][8][128]
constexpr size_t FLAGS_BYTES = 32768;

typedef _Float16 half2v __attribute__((ext_vector_type(2)));
typedef _Float16 half4v __attribute__((ext_vector_type(4)));

__device__ __forceinline__ float wave_sum4(float v) {
    // Sum across lanes {l, l^16, l^32, l^48} — the 4 k-subgroups in a wave.
    v += __shfl_xor(v, 16);
    v += __shfl_xor(v, 32);
    return v;
}

__global__ __launch_bounds__(512, 2) void slstm_persist(
    const float* __restrict__ x,
    const float* __restrict__ Wf, const float* __restrict__ bfv,
    const float* __restrict__ Wi, const float* __restrict__ biv,
    const float* __restrict__ Wo, const float* __restrict__ bov,
    const float* __restrict__ Wz, const float* __restrict__ bzv,
    const float* __restrict__ Rf, const float* __restrict__ Ri,
    const float* __restrict__ Ro, const float* __restrict__ Rz,
    const float* __restrict__ fcw, const float* __restrict__ fcb,
    int* flags, unsigned long long* hbuf,
    float* __restrict__ out)
{
    const int tid  = threadIdx.x;
    // XCD-aware swizzle: all 16 jb-blocks of one bb land on one XCD (perf only;
    // correctness never depends on placement — exchange is agent-scope).
    const int xcd  = blockIdx.x & 7;
    const int slot = blockIdx.x >> 3;        // 0..31
    const int bb   = xcd * 2 + (slot & 1);   // 0..15
    const int jb   = slot >> 1;              // 0..15

    const int kg   = tid >> 4;               // 0..31 k-group
    const int colg = tid & 15;               // 0..15 col-group
    const int k0   = kg * NK;

    // ---------------- prologue: stationary weights -> f16 pair registers ----
    half2v wpk[NC][NK / 2];
    #pragma unroll
    for (int ci = 0; ci < NC; ++ci) {
        const int cc   = colg * NC + ci;         // 0..127
        const int g    = cc >> 5;                // gate
        const int hcol = jb * 32 + (cc & 31);    // global H column
        const float* Wg = (g == 0) ? Wf : (g == 1) ? Wi : (g == 2) ? Wo : Wz;
        const float* Rg = (g == 0) ? Rf : (g == 1) ? Ri : (g == 2) ? Ro : Rz;
        #pragma unroll
        for (int j = 0; j < NK / 2; ++j) {
            const int k = k0 + 2 * j;            // even; pair never spans 256
            float w0, w1;
            if (k < Fdim) {
                w0 = Wg[(size_t)k * Hdim + hcol];
                w1 = Wg[(size_t)(k + 1) * Hdim + hcol];
            } else {
                w0 = Rg[(size_t)(k - Fdim) * Hdim + hcol];
                w1 = Rg[(size_t)(k + 1 - Fdim) * Hdim + hcol];
            }
            wpk[ci][j] = half2v{(_Float16)w0, (_Float16)w1};   // RTN
        }
    }

    // cell-update thread identity (tid < 256): (ub, uhc)
    const int ub  = tid >> 5;                // 0..7
    const int uhc = tid & 31;                // 0..31
    float bias_f = 0.f, bias_i = 0.f, bias_o = 0.f, bias_z = 0.f;
    if (tid < 256) {
        bias_f = bfv[jb * 32 + uhc];
        bias_i = biv[jb * 32 + uhc];
        bias_o = bov[jb * 32 + uhc];
        bias_z = bzv[jb * 32 + uhc];
    }
    float c_st = 0.f, n_st = 0.f;

    __shared__ _Float16 in_s[NB][Kdim];          // 12 KB  f16 [x | h]
    __shared__ float    part_s[8][NB][CC];       // 32 KB  per-wave partials

    // ---- preamble: stage x_0 (f32->f16), zero h region ----
    {
        const int b  = tid >> 6;
        const int f4 = tid & 63;
        float4 v = *reinterpret_cast<const float4*>(
            x + ((size_t)(bb * NB + b) * Tdim + 0) * Fdim + f4 * 4);
        *reinterpret_cast<half4v*>(&in_s[b][f4 * 4]) =
            half4v{(_Float16)v.x, (_Float16)v.y, (_Float16)v.z, (_Float16)v.w};
        const int row = tid >> 6;
        const int u0  = (tid & 63) * 2;          // u64 index 0..126
        *reinterpret_cast<unsigned long long*>(&in_s[row][Fdim + u0 * 4])     = 0ull;
        *reinterpret_cast<unsigned long long*>(&in_s[row][Fdim + u0 * 4 + 4]) = 0ull;
    }
    __syncthreads();

    for (int t = 0; t < Tdim; ++t) {
        // ---- dot2 inner loop: 768 fdot2 (1536 MACs) per thread ----
        float acc[NC][NB];
        #pragma unroll
        for (int ci = 0; ci < NC; ++ci)
            #pragma unroll
            for (int b = 0; b < NB; ++b) acc[ci][b] = 0.f;

        #pragma unroll
        for (int b = 0; b < NB; ++b) {
            const half2v* p = reinterpret_cast<const half2v*>(&in_s[b][k0]);
            half2v hp[12];
            #pragma unroll
            for (int j = 0; j < 12; ++j) hp[j] = p[j];
            #pragma unroll
            for (int ci = 0; ci < NC; ++ci) {
                #pragma unroll
                for (int j = 0; j < NK / 2; ++j) {
                    acc[ci][b] = __builtin_amdgcn_fdot2(
                        wpk[ci][j], hp[j], acc[ci][b], false);
                }
            }
        }

        // ---- reduce across the 4 k-subgroups within the wave ----
        #pragma unroll
        for (int ci = 0; ci < NC; ++ci)
            #pragma unroll
            for (int b = 0; b < NB; ++b)
                acc[ci][b] = wave_sum4(acc[ci][b]);

        // each of the 4 duplicate lane-groups writes 2 batch rows
        {
            const int wv  = tid >> 6;
            const int kgl = (tid >> 4) & 3;
            #pragma unroll
            for (int bs = 0; bs < 2; ++bs) {
                const int b = kgl * 2 + bs;
                #pragma unroll
                for (int cp = 0; cp < NC / 2; ++cp) {
                    float2 w2 = make_float2(acc[2 * cp][b], acc[2 * cp + 1][b]);
                    *reinterpret_cast<float2*>(&part_s[wv][b][colg * NC + 2 * cp]) = w2;
                }
            }
        }
        __syncthreads();

        // ---- cross-wave reduce + bias + cell update + packed h store ----
        if (tid < 256) {
            float pre[4];
            #pragma unroll
            for (int g = 0; g < 4; ++g) {
                float s = 0.f;
                #pragma unroll
                for (int w = 0; w < 8; ++w) s += part_s[w][ub][g * 32 + uhc];
                pre[g] = s;
            }
            pre[0] += bias_f; pre[1] += bias_i; pre[2] += bias_o; pre[3] += bias_z;

            float o  = 1.0f / (1.0f + __expf(-pre[2]));
            float z  = tanhf(pre[3]);
            float fh = __expf(fminf(pre[0], CLAMPc));
            float ih = __expf(fminf(pre[1], CLAMPc));
            float denom = fh + ih + EPSc;
            float f  = fh / denom;
            float ii = ih / denom;
            c_st = f * c_st + ii * z;
            n_st = f * n_st + ii;
            float hval = o * (c_st / (n_st + EPSc));

            // pack 4 cols -> u64 (waves 0-3 fully active; shfl well-defined)
            float h1 = __shfl_xor(hval, 1);
            half2v hp2 = half2v{(_Float16)hval, (_Float16)h1};
            unsigned pck = __builtin_bit_cast(unsigned, hp2);
            unsigned qck = (unsigned)__shfl_xor((int)pck, 2);
            if ((uhc & 3) == 0) {
                unsigned long long v64 =
                    (unsigned long long)pck | ((unsigned long long)qck << 32);
                __hip_atomic_store(
                    &hbuf[(((size_t)(t & 1) * 16 + bb) * 8 + ub) * 128 + ((jb * 32 + uhc) >> 2)],
                    v64, __ATOMIC_RELAXED, __HIP_MEMORY_SCOPE_AGENT);
            }
        }

        // ---- stage x_{t+1} (independent of exchange; dot2 of step t is done) ----
        if (t + 1 < Tdim) {
            const int b  = tid >> 6;
            const int f4 = tid & 63;
            float4 v = *reinterpret_cast<const float4*>(
                x + ((size_t)(bb * NB + b) * Tdim + (t + 1)) * Fdim + f4 * 4);
            *reinterpret_cast<half4v*>(&in_s[b][f4 * 4]) =
                half4v{(_Float16)v.x, (_Float16)v.y, (_Float16)v.z, (_Float16)v.w};
        }

        __syncthreads();   // drains vmcnt(0): all agent h-stores acked at coherence point

        if (tid == 0)
            __hip_atomic_store(&flags[(bb * 16 + jb) * 32], t + 1,
                               __ATOMIC_RELAXED, __HIP_MEMORY_SCOPE_AGENT);
        if (tid < 16) {
            // parallel spin: one thread per group member, each flag on its own line
            while (__hip_atomic_load(&flags[(bb * 16 + tid) * 32],
                                     __ATOMIC_RELAXED, __HIP_MEMORY_SCOPE_AGENT) < t + 1) {}
        }
        __syncthreads();

        // ---- gather packed h (2 x u64 per thread) -> in_s h region ----
        {
            const int row = tid >> 6;
            const int u0  = (tid & 63) * 2;
            unsigned long long* src =
                &hbuf[(((size_t)(t & 1) * 16 + bb) * 8 + row) * 128];
            unsigned long long a = __hip_atomic_load(&src[u0],
                                __ATOMIC_RELAXED, __HIP_MEMORY_SCOPE_AGENT);
            unsigned long long b = __hip_atomic_load(&src[u0 + 1],
                                __ATOMIC_RELAXED, __HIP_MEMORY_SCOPE_AGENT);
            *reinterpret_cast<unsigned long long*>(&in_s[row][Fdim + u0 * 4])     = a;
            *reinterpret_cast<unsigned long long*>(&in_s[row][Fdim + u0 * 4 + 4]) = b;
        }
        __syncthreads();
    }

    // ---- final fc from in_s (final h, f16): out[b] = tanh(h . fc_w + fc_b) ----
    if (jb == 0) {
        const int w = tid >> 6;              // one wave per batch row
        const int l = tid & 63;
        float p = 0.f;
        #pragma unroll
        for (int s = 0; s < 8; ++s)
            p += (float)in_s[w][Fdim + l + s * 64] * fcw[l + s * 64];
        p += __shfl_xor(p, 32);
        p += __shfl_xor(p, 16);
        p += __shfl_xor(p, 8);
        p += __shfl_xor(p, 4);
        p += __shfl_xor(p, 2);
        p += __shfl_xor(p, 1);
        if (l == 0) out[bb * NB + w] = tanhf(p + fcb[0]);
    }
}

extern "C" void kernel_launch(void* const* d_in, const int* in_sizes, int n_in,
                              void* d_out, int out_size, void* d_ws, size_t ws_size,
                              hipStream_t stream) {
    const float* x   = (const float*)d_in[0];
    const float* Wf  = (const float*)d_in[1];
    const float* bf_ = (const float*)d_in[2];
    const float* Wi  = (const float*)d_in[3];
    const float* bi_ = (const float*)d_in[4];
    const float* Wo  = (const float*)d_in[5];
    const float* bo_ = (const float*)d_in[6];
    const float* Wz  = (const float*)d_in[7];
    const float* bz_ = (const float*)d_in[8];
    const float* Rf  = (const float*)d_in[9];
    const float* Ri  = (const float*)d_in[10];
    const float* Ro  = (const float*)d_in[11];
    const float* Rz  = (const float*)d_in[12];
    const float* fcw = (const float*)d_in[13];
    const float* fcb = (const float*)d_in[14];

    int* flags = (int*)d_ws;
    unsigned long long* hbuf =
        (unsigned long long*)((char*)d_ws + FLAGS_BYTES);
    float* o = (float*)d_out;

    // zero the flag region (ws is poisoned 0xAA before every timed launch)
    hipMemsetAsync(d_ws, 0, FLAGS_BYTES, stream);

    void* args[] = { &x, &Wf, &bf_, &Wi, &bi_, &Wo, &bo_, &Wz, &bz_,
                     &Rf, &Ri, &Ro, &Rz, &fcw, &fcb, &flags, &hbuf, &o };

    hipLaunchCooperativeKernel(reinterpret_cast<void*>(slstm_persist),
                               dim3(256), dim3(512), args, 0, stream);
}